// Round 11
// baseline (214.522 us; speedup 1.0000x reference)
//
#include <hip/hip_runtime.h>
#include <hip/hip_bf16.h>

using u16 = unsigned short;
using u32 = unsigned int;
typedef short bf16x8 __attribute__((ext_vector_type(8)));
typedef float f32x4 __attribute__((ext_vector_type(4)));
typedef u16 u16x8 __attribute__((ext_vector_type(8)));
typedef u16 u16x4 __attribute__((ext_vector_type(4)));

#define B_ 4
#define T_ 1024
#define S_ 1024
#define C_ 1024
#define H_ 16
#define D_ 64
// softmax in exp2 domain: scale' = C^-0.5 * log2(e)
#define SCALE_LOG2E 0.0450842200f

#define KSTR  72   // attn LDS row stride (u16) for 64-wide tiles: 144 B (16B-aligned)

__device__ __forceinline__ u16 f2bf(float f) {
    __hip_bfloat16 h = __float2bfloat16(f);
    u16 u; __builtin_memcpy(&u, &h, 2); return u;
}
__device__ __forceinline__ float bf2f(u16 u) {
    __hip_bfloat16 h; __builtin_memcpy(&h, &u, 2);
    return __bfloat162float(h);
}
__device__ __forceinline__ u16x8 ldg8(const u16* p) { return *reinterpret_cast<const u16x8*>(p); }
__device__ __forceinline__ void sts8(u16* p, u16x8 v) { *reinterpret_cast<u16x8*>(p) = v; }
__device__ __forceinline__ bf16x8 lds8(const u16* p) { return *reinterpret_cast<const bf16x8*>(p); }

// async global->LDS DMA, 16 B per lane. g: PER-LANE global addr; l: WAVE-UNIFORM
// LDS base (HW writes lane i at l + i*16 B). Tracked by vmcnt; __syncthreads drains.
__device__ __forceinline__ void gload16(const u16* g, u16* l) {
    __builtin_amdgcn_global_load_lds(
        (const __attribute__((address_space(1))) u32*)g,
        (__attribute__((address_space(3))) u32*)l, 16, 0, 0);
}

// ---------------------------------------------------------------------------
// Fused prep, grid (16,16,6):
//   z=0..2 : W[h][c][d] fp32 -> Wt[h][d][c] bf16  (Wq/Wk/Wv)
//   z=3    : Wo fp32 -> hi/lo bf16 split
//   z=4/5  : x / y_enc fp32 -> bf16
// ---------------------------------------------------------------------------
__global__ __launch_bounds__(256) void prep_kernel(const float* __restrict__ x,
                                                   const float* __restrict__ yenc,
                                                   const float* __restrict__ Wq,
                                                   const float* __restrict__ Wk,
                                                   const float* __restrict__ Wv,
                                                   const float* __restrict__ Wo,
                                                   u16* __restrict__ xbf,
                                                   u16* __restrict__ ybf,
                                                   u16* __restrict__ wtq,
                                                   u16* __restrict__ wtk,
                                                   u16* __restrict__ wtv,
                                                   u16* __restrict__ wohi,
                                                   u16* __restrict__ wolo) {
    const int z = blockIdx.z;
    const int t = threadIdx.x;
    if (z < 3) {
        __shared__ float ldsT[64][65];
        const float* W = (z == 0) ? Wq : (z == 1) ? Wk : Wv;
        u16* Wt = (z == 0) ? wtq : (z == 1) ? wtk : wtv;
        const int c0 = blockIdx.x * 64;
        const int h  = blockIdx.y;
        const float* Wh = W + (size_t)h * C_ * D_;
        u16* Wth = Wt + (size_t)h * D_ * C_;
        {
            int c = t >> 2;
            int d0 = (t & 3) * 16;
            #pragma unroll
            for (int q = 0; q < 4; ++q) {
                float4 v = *reinterpret_cast<const float4*>(Wh + (size_t)(c0 + c) * D_ + d0 + q * 4);
                ldsT[d0 + q * 4 + 0][c] = v.x;
                ldsT[d0 + q * 4 + 1][c] = v.y;
                ldsT[d0 + q * 4 + 2][c] = v.z;
                ldsT[d0 + q * 4 + 3][c] = v.w;
            }
        }
        __syncthreads();
        {
            int d = t >> 2;
            int cq = (t & 3) * 16;
            u16x8 o0, o1;
            #pragma unroll
            for (int j = 0; j < 8; ++j) o0[j] = f2bf(ldsT[d][cq + j]);
            #pragma unroll
            for (int j = 0; j < 8; ++j) o1[j] = f2bf(ldsT[d][cq + 8 + j]);
            *reinterpret_cast<u16x8*>(Wth + (size_t)d * C_ + c0 + cq) = o0;
            *reinterpret_cast<u16x8*>(Wth + (size_t)d * C_ + c0 + cq + 8) = o1;
        }
    } else if (z == 3) {
        int bid = blockIdx.y * 16 + blockIdx.x;
        #pragma unroll
        for (int it = 0; it < 4; ++it) {
            int i = (bid * 4 + it) * 256 + t;   // < C*C/4 = 262144
            float4 v = reinterpret_cast<const float4*>(Wo)[i];
            float vv[4] = {v.x, v.y, v.z, v.w};
            u16x4 hh, ll;
            #pragma unroll
            for (int j = 0; j < 4; ++j) {
                u16 hb = f2bf(vv[j]);
                hh[j] = hb;
                ll[j] = f2bf(vv[j] - bf2f(hb));
            }
            reinterpret_cast<u16x4*>(wohi)[i] = hh;
            reinterpret_cast<u16x4*>(wolo)[i] = ll;
        }
    } else {
        const float* src = (z == 4) ? x : yenc;
        u16* dst = (z == 4) ? xbf : ybf;
        int bid = blockIdx.y * 16 + blockIdx.x;
        #pragma unroll
        for (int it = 0; it < 16; ++it) {
            int i = (bid * 16 + it) * 256 + t;  // < 4M/4 = 1048576
            float4 v = reinterpret_cast<const float4*>(src)[i];
            u16x4 o;
            o[0] = f2bf(v.x); o[1] = f2bf(v.y); o[2] = f2bf(v.z); o[3] = f2bf(v.w);
            reinterpret_cast<u16x4*>(dst)[i] = o;
        }
    }
}

// ---------------------------------------------------------------------------
// Fused QKV projection, bf16 MFMA, tile 128x128, BK=32, grid (8, 32, 3).
// global_load_lds (16B) staging into LINEAR LDS [row][32] bf16, double-buffered;
// next-tile DMA issued before compute, one __syncthreads per k-step (m97 structure).
// z=0: xbf*wtq -> qb[b,h,t,d]; z=1: ybf*wtk -> kb; z=2: ybf*wtv -> vtb[b,h,d,s]
// ---------------------------------------------------------------------------
__global__ __launch_bounds__(256) void proj_mfma_kernel(const u16* __restrict__ xbf,
                                                        const u16* __restrict__ ybf,
                                                        const u16* __restrict__ wtq,
                                                        const u16* __restrict__ wtk,
                                                        const u16* __restrict__ wtv,
                                                        u16* __restrict__ qb,
                                                        u16* __restrict__ kb,
                                                        u16* __restrict__ vtb) {
    __shared__ __align__(16) u16 Al[2][128 * 32];
    __shared__ __align__(16) u16 Bl[2][128 * 32];

    const int z = blockIdx.z;
    const u16* Xb = (z == 0) ? xbf : ybf;
    const u16* Wt = (z == 0) ? wtq : (z == 1) ? wtk : wtv;
    u16* out      = (z == 0) ? qb  : (z == 1) ? kb  : vtb;
    const bool transposed = (z == 2);

    const int n0  = blockIdx.x * 128;
    const int i0  = blockIdx.y * 128;
    const int tid = threadIdx.x;
    const int lane = tid & 63, w = tid >> 6;
    const int g = lane >> 4, li = lane & 15;
    const int wm = (w >> 1) * 64, wn = (w & 1) * 64;

    // DMA lane mapping: lane l -> row l>>2 within a 16-row chunk, col (l&3)*8 u16
    const int sro = lane >> 2, sco = (lane & 3) * 8;

    // wave w stages chunks c = 2w, 2w+1 of A and B (16 rows each)
    #define STAGE_PROJ(buf, k0)                                                        \
        {                                                                              \
            _Pragma("unroll")                                                          \
            for (int i_ = 0; i_ < 2; ++i_) {                                           \
                int c_ = w * 2 + i_;                                                   \
                gload16(Xb + (size_t)(i0 + 16 * c_ + sro) * C_ + (k0) + sco,           \
                        &Al[buf][16 * c_ * 32]);                                       \
                gload16(Wt + (size_t)(n0 + 16 * c_ + sro) * C_ + (k0) + sco,           \
                        &Bl[buf][16 * c_ * 32]);                                       \
            }                                                                          \
        }

    // prologue: tile k0=0 -> buf 0
    STAGE_PROJ(0, 0)
    __syncthreads();

    f32x4 acc[4][4] = {};
    int cur = 0;
    for (int k0 = 0; k0 < C_; k0 += 32) {
        if (k0 + 32 < C_) STAGE_PROJ(cur ^ 1, k0 + 32)   // async, lands before next barrier

        bf16x8 a[4], b[4];
        #pragma unroll
        for (int mf = 0; mf < 4; ++mf)
            a[mf] = lds8(&Al[cur][(wm + mf * 16 + li) * 32 + g * 8]);
        #pragma unroll
        for (int nf = 0; nf < 4; ++nf)
            b[nf] = lds8(&Bl[cur][(wn + nf * 16 + li) * 32 + g * 8]);
        #pragma unroll
        for (int mf = 0; mf < 4; ++mf)
            #pragma unroll
            for (int nf = 0; nf < 4; ++nf)
                acc[mf][nf] = __builtin_amdgcn_mfma_f32_16x16x32_bf16(a[mf], b[nf], acc[mf][nf], 0, 0, 0);

        __syncthreads();   // drains vmcnt (DMA) + lgkm; buffers swap safely
        cur ^= 1;
    }

    if (!transposed) {
        #pragma unroll
        for (int mf = 0; mf < 4; ++mf) {
            int gi = i0 + wm + mf * 16 + g * 4;
            #pragma unroll
            for (int r = 0; r < 4; ++r) {
                int m = gi + r;
                int b = m >> 10, tt = m & 1023;
                #pragma unroll
                for (int nf = 0; nf < 4; ++nf) {
                    int n = n0 + wn + nf * 16 + li;
                    int h = n >> 6, d = n & 63;
                    out[(((size_t)(b * H_ + h) * T_) + tt) * D_ + d] = f2bf(acc[mf][nf][r]);
                }
            }
        }
    } else {
        #pragma unroll
        for (int mf = 0; mf < 4; ++mf) {
            int gi = i0 + wm + mf * 16 + g * 4;
            int b = gi >> 10, s = gi & 1023;
            #pragma unroll
            for (int nf = 0; nf < 4; ++nf) {
                int n = n0 + wn + nf * 16 + li;
                int h = n >> 6, d = n & 63;
                u16x4 o;
                #pragma unroll
                for (int r = 0; r < 4; ++r) o[r] = f2bf(acc[mf][nf][r]);
                *reinterpret_cast<u16x4*>(out + (((size_t)(b * H_ + h) * D_) + d) * S_ + s) = o;
            }
        }
    }
}

// ---------------------------------------------------------------------------
// Flash attention, bf16 MFMA, max-free exp2 softmax with deferred row-sum.
// Block = 128 Q-rows x (h, b), 8 waves (wave owns 16 rows), KVBLK=64.
// Register-prefetch + double-buffered K/V (ONE barrier per tile); P write/read
// split in halves so the first PV block overlaps the second P-write burst.
// ---------------------------------------------------------------------------
__global__ __launch_bounds__(512) void attn_mfma_kernel(const u16* __restrict__ Q,
                                                        const u16* __restrict__ K,
                                                        const u16* __restrict__ Vt,
                                                        u16* __restrict__ out_hi,
                                                        u16* __restrict__ out_lo) {
    __shared__ __align__(16) u16 Kl[2][64 * KSTR];  // [s][d]
    __shared__ __align__(16) u16 Vl[2][64 * KSTR];  // [d][s]
    __shared__ __align__(16) u16 Pl[8][16 * KSTR];  // per-wave [t][s]

    const int t0  = blockIdx.x * 128;
    const int h   = blockIdx.y;
    const int b   = blockIdx.z;
    const int tid = threadIdx.x;
    const int lane = tid & 63, w = tid >> 6;
    const int g = lane >> 4, li = lane & 15;

    const size_t bh = (size_t)(b * H_ + h);
    const u16* Qp = Q  + bh * T_ * D_;
    const u16* Kp = K  + bh * S_ * D_;
    const u16* Vp = Vt + bh * D_ * S_;

    bf16x8 qf[2];
    #pragma unroll
    for (int ks = 0; ks < 2; ++ks)
        qf[ks] = *reinterpret_cast<const bf16x8*>(
            Qp + (size_t)(t0 + w * 16 + li) * D_ + ks * 32 + g * 8);

    const int sr = tid >> 3, sc = (tid & 7) * 8;
    const u16* kBase = Kp + (size_t)sr * D_ + sc;   // +s0*D_ per tile
    const u16* vBase = Vp + (size_t)sr * S_ + sc;   // +s0 per tile

    // prologue: tile 0 -> buf 0
    u16x8 rk = ldg8(kBase);
    u16x8 rv = ldg8(vBase);
    sts8(&Kl[0][sr * KSTR + sc], rk);
    sts8(&Vl[0][sr * KSTR + sc], rv);
    __syncthreads();

    float lsum[4] = {};
    f32x4 accO[4] = {};
    int cur = 0;

    for (int s0 = 0; s0 < S_; s0 += 64) {
        const bool has_next = (s0 + 64 < S_);
        if (has_next) {   // issue next-tile global loads early
            rk = ldg8(kBase + (size_t)(s0 + 64) * D_);
            rv = ldg8(vBase + s0 + 64);
        }

        // QK^T: s = s0 + nf*16 + li, t = t0 + w*16 + g*4 + r
        f32x4 scf[4] = {};
        #pragma unroll
        for (int nf = 0; nf < 4; ++nf)
            #pragma unroll
            for (int ks = 0; ks < 2; ++ks) {
                bf16x8 kf = lds8(&Kl[cur][(nf * 16 + li) * KSTR + ks * 32 + g * 8]);
                scf[nf] = __builtin_amdgcn_mfma_f32_16x16x32_bf16(qf[ks], kf, scf[nf], 0, 0, 0);
            }

        // max-free exp2 numerator; P written/consumed in two halves
        u16* Pw = Pl[w];
        #pragma unroll
        for (int nf = 0; nf < 2; ++nf)        // cols 0-31
            #pragma unroll
            for (int r = 0; r < 4; ++r) {
                float p = exp2f(scf[nf][r] * SCALE_LOG2E);
                lsum[r] += p;
                Pw[(g * 4 + r) * KSTR + nf * 16 + li] = f2bf(p);
            }
        {
            bf16x8 pf0 = lds8(&Pl[w][li * KSTR + g * 8]);            // k = 0-31
            #pragma unroll
            for (int nf = 0; nf < 4; ++nf) {
                bf16x8 vf = lds8(&Vl[cur][(nf * 16 + li) * KSTR + g * 8]);
                accO[nf] = __builtin_amdgcn_mfma_f32_16x16x32_bf16(pf0, vf, accO[nf], 0, 0, 0);
            }
        }
        #pragma unroll
        for (int nf = 2; nf < 4; ++nf)        // cols 32-63
            #pragma unroll
            for (int r = 0; r < 4; ++r) {
                float p = exp2f(scf[nf][r] * SCALE_LOG2E);
                lsum[r] += p;
                Pw[(g * 4 + r) * KSTR + nf * 16 + li] = f2bf(p);
            }
        {
            bf16x8 pf1 = lds8(&Pl[w][li * KSTR + 32 + g * 8]);       // k = 32-63
            #pragma unroll
            for (int nf = 0; nf < 4; ++nf) {
                bf16x8 vf = lds8(&Vl[cur][(nf * 16 + li) * KSTR + 32 + g * 8]);
                accO[nf] = __builtin_amdgcn_mfma_f32_16x16x32_bf16(pf1, vf, accO[nf], 0, 0, 0);
            }
        }

        if (has_next) {   // write prefetched tile into the other buffer
            sts8(&Kl[cur ^ 1][sr * KSTR + sc], rk);
            sts8(&Vl[cur ^ 1][sr * KSTR + sc], rv);
        }
        __syncthreads();
        cur ^= 1;
    }

    // single row-sum reduce across the 16 li lanes
    #pragma unroll
    for (int r = 0; r < 4; ++r) {
        #pragma unroll
        for (int off = 1; off < 16; off <<= 1)
            lsum[r] += __shfl_xor(lsum[r], off, 64);
    }

    // normalize, hi/lo split, store concat layout [b*T+t][h*64+d]
    #pragma unroll
    for (int r = 0; r < 4; ++r) {
        float inv = 1.0f / lsum[r];
        int tt = t0 + w * 16 + g * 4 + r;
        u16* dh = out_hi + ((size_t)(b * T_) + tt) * C_ + h * D_;
        u16* dl = out_lo + ((size_t)(b * T_) + tt) * C_ + h * D_;
        #pragma unroll
        for (int nf = 0; nf < 4; ++nf) {
            float v = accO[nf][r] * inv;
            u16 hb = f2bf(v);
            dh[nf * 16 + li] = hb;
            dl[nf * 16 + li] = f2bf(v - bf2f(hb));
        }
    }
}

// ---------------------------------------------------------------------------
// Output projection: 3-product hi/lo split GEMM, tile 128x64, BK=32,
// 256 threads / 4 waves (2x2, wave 64x32), grid (16,32)=512 blocks = 2/CU.
// global_load_lds staging into LINEAR LDS, double-buffered, one barrier/k-step.
// ---------------------------------------------------------------------------
__global__ __launch_bounds__(256) void outproj_mfma_kernel(const u16* __restrict__ Ahi,
                                                           const u16* __restrict__ Alo,
                                                           const u16* __restrict__ Bhi,
                                                           const u16* __restrict__ Blo,
                                                           const float* __restrict__ bo,
                                                           float* __restrict__ out) {
    __shared__ __align__(16) u16 AH[2][128 * 32];
    __shared__ __align__(16) u16 AL[2][128 * 32];
    __shared__ __align__(16) u16 BH[2][64 * 32];
    __shared__ __align__(16) u16 BL[2][64 * 32];

    const int n0  = blockIdx.x * 64;
    const int i0  = blockIdx.y * 128;
    const int tid = threadIdx.x;
    const int lane = tid & 63, w = tid >> 6;
    const int g = lane >> 4, li = lane & 15;
    const int wm = (w >> 1) * 64, wn = (w & 1) * 32;

    const int sro = lane >> 2, sco = (lane & 3) * 8;

    // wave w stages: AH/AL chunks {2w, 2w+1}, BH/BL chunk {w} (16 rows each)
    #define STAGE_OUTP(buf, k0)                                                        \
        {                                                                              \
            _Pragma("unroll")                                                          \
            for (int i_ = 0; i_ < 2; ++i_) {                                           \
                int c_ = w * 2 + i_;                                                   \
                gload16(Ahi + (size_t)(i0 + 16 * c_ + sro) * C_ + (k0) + sco,          \
                        &AH[buf][16 * c_ * 32]);                                       \
                gload16(Alo + (size_t)(i0 + 16 * c_ + sro) * C_ + (k0) + sco,          \
                        &AL[buf][16 * c_ * 32]);                                       \
            }                                                                          \
            gload16(Bhi + (size_t)(n0 + 16 * w + sro) * C_ + (k0) + sco,               \
                    &BH[buf][16 * w * 32]);                                            \
            gload16(Blo + (size_t)(n0 + 16 * w + sro) * C_ + (k0) + sco,               \
                    &BL[buf][16 * w * 32]);                                            \
        }

    STAGE_OUTP(0, 0)
    __syncthreads();

    f32x4 acc[4][2] = {};
    int cur = 0;
    for (int k0 = 0; k0 < C_; k0 += 32) {
        if (k0 + 32 < C_) STAGE_OUTP(cur ^ 1, k0 + 32)

        bf16x8 ah[4], al[4], bh[2], bl[2];
        #pragma unroll
        for (int mf = 0; mf < 4; ++mf) {
            ah[mf] = lds8(&AH[cur][(wm + mf * 16 + li) * 32 + g * 8]);
            al[mf] = lds8(&AL[cur][(wm + mf * 16 + li) * 32 + g * 8]);
        }
        #pragma unroll
        for (int nf = 0; nf < 2; ++nf) {
            bh[nf] = lds8(&BH[cur][(wn + nf * 16 + li) * 32 + g * 8]);
            bl[nf] = lds8(&BL[cur][(wn + nf * 16 + li) * 32 + g * 8]);
        }
        #pragma unroll
        for (int mf = 0; mf < 4; ++mf)
            #pragma unroll
            for (int nf = 0; nf < 2; ++nf) {
                acc[mf][nf] = __builtin_amdgcn_mfma_f32_16x16x32_bf16(ah[mf], bh[nf], acc[mf][nf], 0, 0, 0);
                acc[mf][nf] = __builtin_amdgcn_mfma_f32_16x16x32_bf16(ah[mf], bl[nf], acc[mf][nf], 0, 0, 0);
                acc[mf][nf] = __builtin_amdgcn_mfma_f32_16x16x32_bf16(al[mf], bh[nf], acc[mf][nf], 0, 0, 0);
            }

        __syncthreads();
        cur ^= 1;
    }

    float bj[2];
    #pragma unroll
    for (int nf = 0; nf < 2; ++nf) bj[nf] = bo[n0 + wn + nf * 16 + li];
    #pragma unroll
    for (int mf = 0; mf < 4; ++mf) {
        int row = i0 + wm + mf * 16 + g * 4;
        #pragma unroll
        for (int r = 0; r < 4; ++r)
            #pragma unroll
            for (int nf = 0; nf < 2; ++nf)
                out[(size_t)(row + r) * C_ + n0 + wn + nf * 16 + li] = acc[mf][nf][r] + bj[nf];
    }
}

// ---------------------------------------------------------------------------
extern "C" void kernel_launch(void* const* d_in, const int* in_sizes, int n_in,
                              void* d_out, int out_size, void* d_ws, size_t ws_size,
                              hipStream_t stream) {
    const float* x    = (const float*)d_in[0];
    const float* yenc = (const float*)d_in[1];
    const float* Wq   = (const float*)d_in[2];
    const float* Wk   = (const float*)d_in[3];
    const float* Wv   = (const float*)d_in[4];
    const float* Wo   = (const float*)d_in[5];
    const float* bo   = (const float*)d_in[6];
    float* out = (float*)d_out;

    char* ws = (char*)d_ws;
    const size_t MB = 1024 * 1024;
    u16* xbf   = (u16*)(ws + 0 * MB);   // 8 MB  (reused as ahi after projs)
    u16* ybf   = (u16*)(ws + 8 * MB);   // 8 MB  (reused as alo after projs)
    u16* wtq   = (u16*)(ws + 16 * MB);  // 2 MB
    u16* wtk   = (u16*)(ws + 18 * MB);
    u16* wtv   = (u16*)(ws + 20 * MB);
    u16* wohi  = (u16*)(ws + 22 * MB);
    u16* wolo  = (u16*)(ws + 24 * MB);
    u16* qb    = (u16*)(ws + 26 * MB);  // 8 MB [B,H,T,D]
    u16* kb    = (u16*)(ws + 34 * MB);  // 8 MB [B,H,S,D]
    u16* vtb   = (u16*)(ws + 42 * MB);  // 8 MB [B,H,D,S]  -> total 50 MB
    u16* ahi   = xbf;                   // overlap: x/y bf16 dead after projections
    u16* alo   = ybf;

    prep_kernel<<<dim3(16, 16, 6), 256, 0, stream>>>(x, yenc, Wq, Wk, Wv, Wo,
                                                     xbf, ybf, wtq, wtk, wtv, wohi, wolo);

    proj_mfma_kernel<<<dim3(8, 32, 3), 256, 0, stream>>>(xbf, ybf, wtq, wtk, wtv, qb, kb, vtb);

    attn_mfma_kernel<<<dim3(T_ / 128, H_, B_), 512, 0, stream>>>(qb, kb, vtb, ahi, alo);

    outproj_mfma_kernel<<<dim3(16, 32), 256, 0, stream>>>(ahi, alo, wohi, wolo, bo, out);
}